// Round 9
// baseline (254.299 us; speedup 1.0000x reference)
//
#include <hip/hip_runtime.h>

// ---------- constants ----------
#define B_   16
#define C_   256
#define OC_  256
#define H_   64
#define W_   64

typedef __attribute__((ext_vector_type(8))) __bf16 bf16x8;
typedef __attribute__((ext_vector_type(4))) float  f32x4;

__device__ __forceinline__ short f2bf(float f) {
    unsigned u = __float_as_uint(f);
    u += 0x7fffu + ((u >> 16) & 1u);
    return (short)(u >> 16);
}
__device__ __forceinline__ unsigned pk2(float a, float b) {
    return (unsigned(f2bf(a)) & 0xffffu) | (unsigned(f2bf(b)) << 16);
}
__device__ __forceinline__ void gll16(const void* g, void* l) {
    __builtin_amdgcn_global_load_lds(
        (const __attribute__((address_space(1))) unsigned int*)g,
        (__attribute__((address_space(3))) unsigned int*)l,
        16, 0, 0);
}

// ---------- kernel 1: x (fp32, NCHW) -> x_t (bf16, [b][y][x][c]) + pooled atomics ----------
__global__ __launch_bounds__(256) void k_transpose_pool(
        const float* __restrict__ x, short* __restrict__ xt, float* __restrict__ pooled) {
    int y = blockIdx.x, b = blockIdx.y, t = threadIdx.x;
    int si = y >> 4;
    int lane = t & 63, wv = t >> 6;
    int xq = lane & 15, cw = lane >> 4;
    __shared__ float tile[64 * 67];   // stride 67: both phases ~2-way (free)

    for (int cc = 0; cc < 4; ++cc) {
        int cbase = cc * 64;
        if (cc) __syncthreads();
        #pragma unroll
        for (int r = 0; r < 4; ++r) {
            int c_l = r * 16 + wv * 4 + cw;
            float4 v = *(const float4*)&x[(((size_t)b * C_ + cbase + c_l) * H_ + y) * W_ + xq * 4];
            float* tp = &tile[c_l * 67 + xq * 4];
            tp[0] = v.x; tp[1] = v.y; tp[2] = v.z; tp[3] = v.w;
            float s = v.x + v.y + v.z + v.w;       // pooling partial (4 x)
            s += __shfl_xor(s, 1);
            s += __shfl_xor(s, 2);
            if ((lane & 3) == 0)
                atomicAdd(&pooled[((b * 4 + si) * 4 + (xq >> 2)) * 256 + cbase + c_l], s);
        }
        __syncthreads();
        #pragma unroll
        for (int r2 = 0; r2 < 2; ++r2) {
            int u = r2 * 256 + t;
            int xx = u >> 3, cgl = u & 7;
            float f[8];
            #pragma unroll
            for (int j = 0; j < 8; ++j) f[j] = tile[(cgl * 8 + j) * 67 + xx];
            uint4 pkv;
            pkv.x = pk2(f[0], f[1]); pkv.y = pk2(f[2], f[3]);
            pkv.z = pk2(f[4], f[5]); pkv.w = pk2(f[6], f[7]);
            *(uint4*)&xt[(((size_t)b * H_ + y) * W_ + xx) * C_ + cbase + cgl * 8] = pkv;
        }
    }
}

// ---------- kernel 2: routing head -> r[b][k][c] ----------
__global__ __launch_bounds__(256) void k_route(
        const float* __restrict__ pooled, const float* __restrict__ rconv_w,
        const float* __restrict__ rconv_b, const float* __restrict__ fc_w,
        const float* __restrict__ fc_b, float* __restrict__ r_buf) {
    int b = blockIdx.x;
    int t = threadIdx.x;
    __shared__ float pl[16][257];
    __shared__ float y1[256];

    #pragma unroll
    for (int q = 0; q < 16; ++q)
        pl[q][t] = pooled[b * 4096 + q * 256 + t] * (1.0f / 256.0f);
    __syncthreads();
    {
        int rcc = t >> 4, ss = t & 15;
        float acc = rconv_b[rcc];
        #pragma unroll 8
        for (int c = 0; c < 256; ++c)
            acc += pl[ss][c] * rconv_w[rcc * 256 + c];
        y1[rcc * 16 + ss] = fmaxf(acc, 0.f);
    }
    __syncthreads();
    for (int e0 = 0; e0 < 768; e0 += 256) {
        int e = e0 + t;
        float acc = fc_b[e];
        #pragma unroll 8
        for (int q = 0; q < 256; ++q)
            acc += y1[q] * fc_w[(size_t)e * 256 + q];
        acc = fmaxf(acc, 0.f);
        r_buf[(size_t)b * 768 + e] = 1.f / (1.f + __expf(-acc));
    }
}

// ---------- kernel 3: combine experts -> wcomb (fragment order), E read ONCE ----------
// Layout: [b][tap9][ccs8][og16] x 1KB-fragment [ol16][quad4][ch8] (shorts).
__global__ __launch_bounds__(256) void k_combine(
        const float* __restrict__ E, const float* __restrict__ r_buf,
        short* __restrict__ wcomb) {
    int o = blockIdx.x;        // 0..255
    int t = threadIdx.x;
    __shared__ float eT[3][2304];
    #pragma unroll
    for (int k = 0; k < 3; ++k)
        #pragma unroll
        for (int q = 0; q < 9; ++q)
            eT[k][q * 256 + t] = E[((size_t)k * OC_ + o) * 2304 + q * 256 + t];
    __syncthreads();
    int c = t;
    float e0[9], e1[9], e2[9];
    #pragma unroll
    for (int tap = 0; tap < 9; ++tap) {
        e0[tap] = eT[0][c * 9 + tap];
        e1[tap] = eT[1][c * 9 + tap];
        e2[tap] = eT[2][c * 9 + tap];
    }
    int ccs = c >> 5;                                          // cc*2+s (0..7)
    int sub = (o & 15) * 32 + ((c >> 3) & 3) * 8 + (c & 7);    // ol/quad/ch
    int og  = o >> 4;
    for (int b = 0; b < 16; ++b) {
        float r0 = r_buf[(size_t)b * 768 + c];
        float r1 = r_buf[(size_t)b * 768 + 256 + c];
        float r2 = r_buf[(size_t)b * 768 + 512 + c];
        short* wo = wcomb + (size_t)b * 589824;
        #pragma unroll
        for (int tap = 0; tap < 9; ++tap) {
            float v = r0 * e0[tap] + r1 * e1[tap] + r2 * e2[tap];
            wo[((tap * 8 + ccs) * 16 + og) * 512 + sub] = f2bf(v);
        }
    }
}

// ---------- kernel 4: implicit-GEMM conv, 3 blocks/CU (12 waves) ----------
// R8 post-mortem (corrected model): LDS traffic is only ~3us/CU-equiv; the
// 74us = 37us MFMA floor at ~50% duty, and 2 waves/SIMD can't fill the
// issue gaps. R9 = R8's proven barrier-free reg-A inner loop with R0's
// 4x4 wave tile: block 128o x 128pos (2 rows), win 4 rows = 32KB, acc 64
// AGPR, P[2][4] ping-pong -> ~150-170 regs -> __launch_bounds__(256,3)
// = 3 blocks/CU = 3 waves/SIMD. Grid 1024, XCD-contiguous (2 b/XCD).
__global__ __launch_bounds__(256, 3) void k_conv(
        const short* __restrict__ xt, const short* __restrict__ wcomb,
        float* __restrict__ out, const short* __restrict__ zbuf) {
    int lin  = blockIdx.x;
    int work = (lin & 7) * 128 + (lin >> 3);  // XCD-contiguous: 2 samples/XCD
    int b      = work >> 6;
    int o_base = ((work >> 5) & 1) * 128;
    int y0     = (work & 31) * 2;             // 2 output rows per block

    int t = threadIdx.x;
    int lane = t & 63, w = t >> 6;
    int quad = lane >> 4, l15 = lane & 15;

    __shared__ __align__(16) short win[4 * 64 * 64];   // rows y0-1..y0+2, 32 KB

    int zoff = (int)(zbuf - xt);               // halo rows redirect into zbuf

    // window staging offsets (8 rounds x 256 threads = 2048 tasks)
    int woff[8];
    #pragma unroll
    for (int r = 0; r < 8; ++r) {
        int u = r * 256 + t;
        int pos = u >> 3, sp = u & 7;
        int wrow = pos >> 6, xc = pos & 63;
        int yy = y0 - 1 + wrow;
        int ss = sp ^ (xc & 7);                 // XOR swizzle at source
        woff[r] = ((unsigned)yy < 64u)
            ? ((b * 64 + yy) * 64 + xc) * 256 + ss * 8
            : zoff;
    }

    int m_base = (w & 1) * 64;
    int ry0    = (w >> 1);                     // output row within pair (0/1)

    // A fragment base (shorts): [b][tap][ccs][og] x [ol][quad][ch]
    const short* pA = wcomb + (size_t)b * 589824
                    + ((o_base + m_base) >> 4) * 512 + l15 * 32 + quad * 8;

    f32x4 acc[4][4];
    #pragma unroll
    for (int i = 0; i < 4; ++i)
        #pragma unroll
        for (int j = 0; j < 4; ++j) acc[i][j] = {0.f, 0.f, 0.f, 0.f};

    for (int cc = 0; cc < 4; ++cc) {
        int ccOff = cc * 64;                   // xt channel offset (shorts)
        int ccA   = cc * 16384;                // A offset (shorts)
        // stage window (direct-to-LDS; prev-cc tail barrier protects reuse)
        #pragma unroll
        for (int r = 0; r < 8; ++r)
            gll16(xt + woff[r] + ccOff, &win[(r * 256 + w * 64) * 8]);

        // preload A phases 0,1 (latency hides under the staging drain)
        bf16x8 P[2][4];
        #pragma unroll
        for (int mb = 0; mb < 4; ++mb) {
            P[0][mb] = *(const bf16x8*)(pA + ccA + mb * 512);
            P[1][mb] = *(const bf16x8*)(pA + ccA + 8192 + mb * 512);
        }
        __syncthreads();   // win ready (drains gll16 + A preloads)

        // 18 phases = 9 taps x 2 k-slots; NO barriers inside.
        #pragma unroll
        for (int ph = 0; ph < 18; ++ph) {
            const int tp = ph >> 1, s = ph & 1;
            const int ti = tp / 3, tj = tp % 3;
            const int cur = ph & 1;
            int slog = s * 4 + quad;

            bf16x8 bv[4];
            #pragma unroll
            for (int nb = 0; nb < 4; ++nb) {
                int xc = nb * 16 + l15 + (tj - 1);
                bool ok = ((unsigned)xc < 64u);
                int xs = ok ? xc : 0;
                int wrow = ry0 + ti;         // 0..3
                bf16x8 v = *(const bf16x8*)&win[(wrow * 64 + xs) * 64
                                                + ((slog ^ (xs & 7)) * 8)];
                bf16x8 zz = {};
                bv[nb] = ok ? v : zz;        // column halo is zero
            }
            __builtin_amdgcn_s_setprio(1);
            #pragma unroll
            for (int mb = 0; mb < 4; ++mb)
                #pragma unroll
                for (int nb = 0; nb < 4; ++nb)
                    acc[mb][nb] = __builtin_amdgcn_mfma_f32_16x16x32_bf16(
                        P[cur][mb], bv[nb], acc[mb][nb], 0, 0, 0);
            __builtin_amdgcn_s_setprio(0);

            // prefetch phase ph+2 into the parity just consumed (coalesced 1KB x4)
            if (ph < 16) {
                const int np = ph + 2, ntp = np >> 1, ns = np & 1;
                #pragma unroll
                for (int mb = 0; mb < 4; ++mb)
                    P[cur][mb] = *(const bf16x8*)(pA + ccA + ntp * 65536
                                                  + ns * 8192 + mb * 512);
            }
        }
        if (cc < 3) __syncthreads();   // all win reads done before restage
    }

    #pragma unroll
    for (int mb = 0; mb < 4; ++mb) {
        #pragma unroll
        for (int nb = 0; nb < 4; ++nb) {
            int xx = nb * 16 + l15;
            int yy = y0 + ry0;
            #pragma unroll
            for (int rg = 0; rg < 4; ++rg) {
                int o = o_base + m_base + mb * 16 + quad * 4 + rg;
                out[(((size_t)b * OC_ + o) * H_ + yy) * W_ + xx] = acc[mb][nb][rg];
            }
        }
    }
}

// ---------- launcher ----------
extern "C" void kernel_launch(void* const* d_in, const int* in_sizes, int n_in,
                              void* d_out, int out_size, void* d_ws, size_t ws_size,
                              hipStream_t stream) {
    const float* x       = (const float*)d_in[0];
    const float* E       = (const float*)d_in[1];
    const float* rconv_w = (const float*)d_in[2];
    const float* rconv_b = (const float*)d_in[3];
    const float* fc_w    = (const float*)d_in[4];
    const float* fc_b    = (const float*)d_in[5];
    float* out = (float*)d_out;

    char* ws = (char*)d_ws;
    short* xt     = (short*)(ws);                    // 32 MiB
    short* wcomb  = (short*)(ws + 33554432);         // 18 MiB (fragment-ordered)
    float* pooled = (float*)(ws + 52428800);         // 256 KiB
    short* zbuf   = (short*)(ws + 52690944);         // 1 KiB zeros (adjacent to pooled)
    float* rbuf   = (float*)(ws + 52692992);         // 48 KiB

    hipMemsetAsync(pooled, 0, 262144 + 1024, stream);   // pooled + zbuf in one node

    k_transpose_pool<<<dim3(64, 16), 256, 0, stream>>>(x, xt, pooled);
    k_route<<<dim3(16), 256, 0, stream>>>(pooled, rconv_w, rconv_b, fc_w, fc_b, rbuf);
    k_combine<<<dim3(256), 256, 0, stream>>>(E, rbuf, wcomb);
    k_conv<<<dim3(1024), 256, 0, stream>>>(xt, wcomb, out, zbuf);
}

// Round 11
// 250.816 us; speedup vs baseline: 1.0139x; 1.0139x over previous
//
#include <hip/hip_runtime.h>

// ---------- constants ----------
#define B_   16
#define C_   256
#define OC_  256
#define H_   64
#define W_   64

typedef __attribute__((ext_vector_type(8)))  __bf16 bf16x8;
typedef __attribute__((ext_vector_type(4)))  float  f32x4;
typedef __attribute__((ext_vector_type(16))) float  f32x16;

__device__ __forceinline__ short f2bf(float f) {
    unsigned u = __float_as_uint(f);
    u += 0x7fffu + ((u >> 16) & 1u);
    return (short)(u >> 16);
}
__device__ __forceinline__ unsigned pk2(float a, float b) {
    return (unsigned(f2bf(a)) & 0xffffu) | (unsigned(f2bf(b)) << 16);
}
__device__ __forceinline__ void gll16(const void* g, void* l) {
    __builtin_amdgcn_global_load_lds(
        (const __attribute__((address_space(1))) unsigned int*)g,
        (__attribute__((address_space(3))) unsigned int*)l,
        16, 0, 0);
}

// ---------- kernel 1: x (fp32, NCHW) -> x_t (bf16, [b][y][x][c]) + pooled atomics ----------
__global__ __launch_bounds__(256) void k_transpose_pool(
        const float* __restrict__ x, short* __restrict__ xt, float* __restrict__ pooled) {
    int y = blockIdx.x, b = blockIdx.y, t = threadIdx.x;
    int si = y >> 4;
    int lane = t & 63, wv = t >> 6;
    int xq = lane & 15, cw = lane >> 4;
    __shared__ float tile[64 * 67];   // stride 67: both phases ~2-way (free)

    for (int cc = 0; cc < 4; ++cc) {
        int cbase = cc * 64;
        if (cc) __syncthreads();
        #pragma unroll
        for (int r = 0; r < 4; ++r) {
            int c_l = r * 16 + wv * 4 + cw;
            float4 v = *(const float4*)&x[(((size_t)b * C_ + cbase + c_l) * H_ + y) * W_ + xq * 4];
            float* tp = &tile[c_l * 67 + xq * 4];
            tp[0] = v.x; tp[1] = v.y; tp[2] = v.z; tp[3] = v.w;
            float s = v.x + v.y + v.z + v.w;       // pooling partial (4 x)
            s += __shfl_xor(s, 1);
            s += __shfl_xor(s, 2);
            if ((lane & 3) == 0)
                atomicAdd(&pooled[((b * 4 + si) * 4 + (xq >> 2)) * 256 + cbase + c_l], s);
        }
        __syncthreads();
        #pragma unroll
        for (int r2 = 0; r2 < 2; ++r2) {
            int u = r2 * 256 + t;
            int xx = u >> 3, cgl = u & 7;
            float f[8];
            #pragma unroll
            for (int j = 0; j < 8; ++j) f[j] = tile[(cgl * 8 + j) * 67 + xx];
            uint4 pkv;
            pkv.x = pk2(f[0], f[1]); pkv.y = pk2(f[2], f[3]);
            pkv.z = pk2(f[4], f[5]); pkv.w = pk2(f[6], f[7]);
            *(uint4*)&xt[(((size_t)b * H_ + y) * W_ + xx) * C_ + cbase + cgl * 8] = pkv;
        }
    }
}

// ---------- kernel 2: routing head -> r[b][k][c] (R0 original) ----------
__global__ __launch_bounds__(256) void k_route(
        const float* __restrict__ pooled, const float* __restrict__ rconv_w,
        const float* __restrict__ rconv_b, const float* __restrict__ fc_w,
        const float* __restrict__ fc_b, float* __restrict__ r_buf) {
    int b = blockIdx.x;
    int t = threadIdx.x;
    __shared__ float pl[16][257];
    __shared__ float y1[256];

    #pragma unroll
    for (int q = 0; q < 16; ++q)
        pl[q][t] = pooled[b * 4096 + q * 256 + t] * (1.0f / 256.0f);
    __syncthreads();
    {
        int rcc = t >> 4, ss = t & 15;
        float acc = rconv_b[rcc];
        #pragma unroll 8
        for (int c = 0; c < 256; ++c)
            acc += pl[ss][c] * rconv_w[rcc * 256 + c];
        y1[rcc * 16 + ss] = fmaxf(acc, 0.f);
    }
    __syncthreads();
    for (int e0 = 0; e0 < 768; e0 += 256) {
        int e = e0 + t;
        float acc = fc_b[e];
        #pragma unroll 8
        for (int q = 0; q < 256; ++q)
            acc += y1[q] * fc_w[(size_t)e * 256 + q];
        acc = fmaxf(acc, 0.f);
        r_buf[(size_t)b * 768 + e] = 1.f / (1.f + __expf(-acc));
    }
}

// ---------- kernel 3: combine experts -> wcomb (32x32x16-fragment order) ----------
// Layout: [b][tap9][ks16][og8] x 512-short fragment [ol32][half2][ch8].
// R10 BUG FIX: sub was ol*32 (2KB span inside a 1KB fragment -> (og,ol>=16)
// clobbered (og+1,ol-16)). Each ol row holds 16 k-shorts -> sub = ol*16+...
// k_conv wave reads the 1KB fragment fully coalesced (lane: l31*16+lh*8).
// k_combine writes: threads c=0..15 cover 16 consecutive shorts = 32B segs.
__global__ __launch_bounds__(256) void k_combine(
        const float* __restrict__ E, const float* __restrict__ r_buf,
        short* __restrict__ wcomb) {
    int o = blockIdx.x;        // 0..255
    int t = threadIdx.x;
    __shared__ float eT[3][2304];
    #pragma unroll
    for (int k = 0; k < 3; ++k)
        #pragma unroll
        for (int q = 0; q < 9; ++q)
            eT[k][q * 256 + t] = E[((size_t)k * OC_ + o) * 2304 + q * 256 + t];
    __syncthreads();
    int c = t;
    float e0[9], e1[9], e2[9];
    #pragma unroll
    for (int tap = 0; tap < 9; ++tap) {
        e0[tap] = eT[0][c * 9 + tap];
        e1[tap] = eT[1][c * 9 + tap];
        e2[tap] = eT[2][c * 9 + tap];
    }
    int ks   = c >> 4;                 // k-slot of 16 ch (0..15)
    int half = (c >> 3) & 1;
    int ch   = c & 7;
    int og   = o >> 5, ol = o & 31;
    int sub  = ol * 16 + half * 8 + ch;          // FIXED: 16 shorts per ol row
    for (int b = 0; b < 16; ++b) {
        float r0 = r_buf[(size_t)b * 768 + c];
        float r1 = r_buf[(size_t)b * 768 + 256 + c];
        float r2 = r_buf[(size_t)b * 768 + 512 + c];
        short* wo = wcomb + (size_t)b * 589824;
        #pragma unroll
        for (int tap = 0; tap < 9; ++tap) {
            float v = r0 * e0[tap] + r1 * e1[tap] + r2 * e2[tap];
            wo[((tap * 16 + ks) * 8 + og) * 512 + sub] = f2bf(v);
        }
    }
}

// ---------- kernel 4: implicit-GEMM conv, 32x32x16 MFMA ----------
// Theory (R9 post-mortem): pipes are ADDITIVE per CU phase-window; shrink
// the terms. 32x32x16 = 2495 TF vs 16x16x32's 2075 (-20% MFMA floor); wave
// tile 128o x 64pos (mb4 x nb2): 2 bv ds_read_b128 per 8 MFMA = 128 FLOP/B
// (2x R8); VALU per phase ~halved. Structure = R8-verbatim: barrier-free
// 36 phases/cc, A from fragment-ordered wcomb via coalesced 1KB loads into
// P[2][4] ping-pong carried across cc, win 48KB clamp-halo, 2 blocks/CU.
// A layout: row=lane&31, k=(lane>>5)*8+j (A,B symmetric -> any common
// bijection is contraction-invariant). C/D: col=lane&31,
// row=(rg&3)+8*(rg>>2)+4*(lane>>5)  [HW-verified m74/m101].
__global__ __launch_bounds__(256, 2) void k_conv(
        const short* __restrict__ xt, const short* __restrict__ wcomb,
        float* __restrict__ out, const short* __restrict__ zbuf) {
    int lin  = blockIdx.x;
    int work = (lin & 7) * 64 + (lin >> 3);   // XCD-contiguous: 2 samples/XCD
    int b      = work >> 5;
    int o_base = ((work >> 4) & 1) * 128;
    int y0     = (work & 15) * 4;             // 4 output rows per block

    int t = threadIdx.x;
    int lane = t & 63, w = t >> 6;            // wave w owns output row y0+w
    int l31 = lane & 31, lh = lane >> 5;

    __shared__ __align__(16) short win[6 * 64 * 64];   // rows y0-1..y0+4, 48 KB

    int zoff = (int)(zbuf - xt);               // halo rows redirect into zbuf

    // window staging offsets (12 rounds x 256 threads = 3072 tasks)
    int woff[12];
    #pragma unroll
    for (int r = 0; r < 12; ++r) {
        int u = r * 256 + t;
        int pos = u >> 3, sp = u & 7;
        int wrow = pos >> 6, xc = pos & 63;
        int yy = y0 - 1 + wrow;
        int ss = sp ^ (xc & 7);                 // XOR swizzle at source
        woff[r] = ((unsigned)yy < 64u)
            ? ((b * 64 + yy) * 64 + xc) * 256 + ss * 8
            : zoff;
    }

    // A fragment base (shorts): [b][tap][ks][og] x [ol][half][ch]
    int og0 = o_base >> 5;
    const short* pA = wcomb + (size_t)b * 589824
                    + og0 * 512 + l31 * 16 + lh * 8;   // FIXED: l31*16

    f32x16 acc[4][2];
    #pragma unroll
    for (int i = 0; i < 4; ++i)
        #pragma unroll
        for (int j = 0; j < 2; ++j)
            #pragma unroll
            for (int q = 0; q < 16; ++q) acc[i][j][q] = 0.f;

    bf16x8 P[2][4];   // ping-pong, carried across cc (cross-cc prefetch)

    for (int cc = 0; cc < 4; ++cc) {
        int ccOff = cc * 64;                   // xt channel offset (shorts)
        // stage window (direct-to-LDS; prev-cc tail barrier protects reuse)
        #pragma unroll
        for (int r = 0; r < 12; ++r)
            gll16(xt + woff[r] + ccOff, &win[(r * 256 + w * 64) * 8]);

        if (cc == 0) {   // preload phases 0,1 (tap0, ks_g 0/1)
            #pragma unroll
            for (int mb = 0; mb < 4; ++mb) {
                P[0][mb] = *(const bf16x8*)(pA + (0 * 16 + 0) * 4096 + mb * 512);
                P[1][mb] = *(const bf16x8*)(pA + (0 * 16 + 1) * 4096 + mb * 512);
            }
        }
        __syncthreads();   // win ready (drains gll16 + A preloads)

        // 36 phases = 9 taps x 4 k-slots(16ch); NO barriers inside.
        #pragma unroll
        for (int ph = 0; ph < 36; ++ph) {
            const int tap = ph >> 2, ks = ph & 3;
            const int ti = tap / 3, tj = tap % 3;
            const int cur = ph & 1;
            const int slot = ks * 2 + lh;       // ch8-slot within cc (0..7)

            bf16x8 bv[2];
            #pragma unroll
            for (int nb = 0; nb < 2; ++nb) {
                int xc = nb * 32 + l31 + (tj - 1);
                bool ok = ((unsigned)xc < 64u);
                int xs = ok ? xc : 0;
                int wrow = w + ti;              // 0..5
                bf16x8 v = *(const bf16x8*)&win[(wrow * 64 + xs) * 64
                                                + ((slot ^ (xs & 7)) * 8)];
                bf16x8 zz = {};
                bv[nb] = ok ? v : zz;           // column halo is zero
            }
            __builtin_amdgcn_s_setprio(1);
            #pragma unroll
            for (int mb = 0; mb < 4; ++mb)
                #pragma unroll
                for (int nb = 0; nb < 2; ++nb)
                    acc[mb][nb] = __builtin_amdgcn_mfma_f32_32x32x16_bf16(
                        P[cur][mb], bv[nb], acc[mb][nb], 0, 0, 0);
            __builtin_amdgcn_s_setprio(0);

            // prefetch phase ph+2 into the parity just consumed (coalesced 1KB x4)
            if (ph < 34) {
                const int np = ph + 2, ntap = np >> 2, nks = np & 3;
                #pragma unroll
                for (int mb = 0; mb < 4; ++mb)
                    P[cur][mb] = *(const bf16x8*)(pA
                        + (ntap * 16 + cc * 4 + nks) * 4096 + mb * 512);
            } else if (cc < 3) {                // cross-cc: next cc ph 0/1
                const int nks = (ph == 34) ? 0 : 1;
                #pragma unroll
                for (int mb = 0; mb < 4; ++mb)
                    P[cur][mb] = *(const bf16x8*)(pA
                        + (0 * 16 + (cc + 1) * 4 + nks) * 4096 + mb * 512);
            }
        }
        if (cc < 3) __syncthreads();   // all win reads done before restage
    }

    // C/D layout (m74/m101): col = lane&31 (pos), row = (rg&3)+8*(rg>>2)+4*lh
    #pragma unroll
    for (int mb = 0; mb < 4; ++mb) {
        #pragma unroll
        for (int nb = 0; nb < 2; ++nb) {
            int xx = nb * 32 + l31;
            int yy = y0 + w;
            #pragma unroll
            for (int rg = 0; rg < 16; ++rg) {
                int o = o_base + mb * 32 + (rg & 3) + ((rg >> 2) * 8) + lh * 4;
                out[(((size_t)b * OC_ + o) * H_ + yy) * W_ + xx] = acc[mb][nb][rg];
            }
        }
    }
}

// ---------- launcher ----------
extern "C" void kernel_launch(void* const* d_in, const int* in_sizes, int n_in,
                              void* d_out, int out_size, void* d_ws, size_t ws_size,
                              hipStream_t stream) {
    const float* x       = (const float*)d_in[0];
    const float* E       = (const float*)d_in[1];
    const float* rconv_w = (const float*)d_in[2];
    const float* rconv_b = (const float*)d_in[3];
    const float* fc_w    = (const float*)d_in[4];
    const float* fc_b    = (const float*)d_in[5];
    float* out = (float*)d_out;

    char* ws = (char*)d_ws;
    short* xt     = (short*)(ws);                    // 32 MiB
    short* wcomb  = (short*)(ws + 33554432);         // 18 MiB (fragment-ordered)
    float* pooled = (float*)(ws + 52428800);         // 256 KiB
    short* zbuf   = (short*)(ws + 52690944);         // 1 KiB zeros (adjacent to pooled)
    float* rbuf   = (float*)(ws + 52692992);         // 48 KiB

    hipMemsetAsync(pooled, 0, 262144 + 1024, stream);   // pooled + zbuf in one node

    k_transpose_pool<<<dim3(64, 16), 256, 0, stream>>>(x, xt, pooled);
    k_route<<<dim3(16), 256, 0, stream>>>(pooled, rconv_w, rconv_b, fc_w, fc_b, rbuf);
    k_combine<<<dim3(256), 256, 0, stream>>>(E, rbuf, wcomb);
    k_conv<<<dim3(512), 256, 0, stream>>>(xt, wcomb, out, zbuf);
}